// Round 16
// baseline (293.285 us; speedup 1.0000x reference)
//
#include <hip/hip_runtime.h>
#include <hip/hip_bf16.h>

#define EMBED 768
#define FFNDIM 3072
#define HEADS 12
#define HDIM  64
#define BB    4
#define TT    2048
#define MTOK  (BB*TT)   // 8192 tokens

typedef __hip_bfloat16 bf16;
typedef __attribute__((ext_vector_type(8))) short short8;
typedef __attribute__((ext_vector_type(4))) float f32x4;
typedef __attribute__((ext_vector_type(16))) float f32x16;
typedef __attribute__((ext_vector_type(4))) unsigned short ushort4v;

__device__ __forceinline__ f32x4 mfma16(short8 a, short8 b, f32x4 c) {
  return __builtin_amdgcn_mfma_f32_16x16x32_bf16(a, b, c, 0, 0, 0);
}
__device__ __forceinline__ f32x16 mfma32(short8 a, short8 b, f32x16 c) {
  return __builtin_amdgcn_mfma_f32_32x32x16_bf16(a, b, c, 0, 0, 0);
}

__device__ __forceinline__ unsigned short f2bf(float f) {
  union { float f; unsigned int u; } v; v.f = f;
  unsigned int u = v.u;
  return (unsigned short)((u + 0x7fffu + ((u >> 16) & 1u)) >> 16);
}

// 2^x via the native transcendental
__device__ __forceinline__ float fexp2(float x) {
#if __has_builtin(__builtin_amdgcn_exp2f)
  return __builtin_amdgcn_exp2f(x);
#else
  return exp2f(x);
#endif
}

// exact-GELU via A&S 7.1.26 erf (|err| <= 1.5e-7, far below bf16 ulp)
__device__ __forceinline__ float gelu_f(float v) {
  const float ax = fabsf(v) * 0.70710678118f;   // |v|/sqrt(2)
  const float t = __builtin_amdgcn_rcpf(1.f + 0.3275911f * ax);
  float p = 1.061405429f;
  p = p * t - 1.453152027f;
  p = p * t + 1.421413741f;
  p = p * t - 0.284496736f;
  p = p * t + 0.254829592f;
  p = p * t;
  const float e = fexp2(-ax * ax * 1.4426950408889634f);  // exp(-x^2)
  float er = 1.f - p * e;
  er = (v < 0.f) ? -er : er;
  return 0.5f * v * (1.f + er);
}

// v_cvt_pk_bf16_f32: pack two f32 -> two bf16 in one dword (lo, hi), RNE
__device__ __forceinline__ unsigned cvtpk(float lo, float hi) {
  unsigned r;
  asm("v_cvt_pk_bf16_f32 %0, %1, %2" : "=v"(r) : "v"(lo), "v"(hi));
  return r;
}
// v_permlane32_swap_b32: vdst[0:31]<->vsrc[32:63] swap
__device__ __forceinline__ void pl32swap(unsigned& vdst, unsigned& vsrc) {
  asm("v_permlane32_swap_b32 %0, %1" : "+v"(vdst), "+v"(vsrc));
}

// async global->LDS, 16B per lane; lds dest is wave-uniform base + lane*16
__device__ __forceinline__ void gl_lds16(const void* g, void* l) {
  __builtin_amdgcn_global_load_lds((const __attribute__((address_space(1))) void*)g,
                                   (__attribute__((address_space(3))) void*)l, 16, 0, 0);
}

// counted vmcnt wait (immediate), fenced so following ops can't hoist above it
template <int N>
__device__ __forceinline__ void wait_vm() {
  asm volatile("s_waitcnt vmcnt(%0)" :: "i"(N) : "memory");
  __builtin_amdgcn_sched_barrier(0);
}
__device__ __forceinline__ void block_barrier() {
  __builtin_amdgcn_sched_barrier(0);
  __builtin_amdgcn_s_barrier();
  __builtin_amdgcn_sched_barrier(0);
}

// q pre-scale: (1/sqrt(64)) * log2(e), so softmax runs in exp2 domain
#define QSCALE 0.18033688011112042f
#define DEFER_THR 11.54f   // 8 nats in log2 units

// ===========================================================================
// FRAGMENT-MAJOR layouts (producer = QKV GEMM epilogue, consumer = flash):
//  Q/K: elem (b,h, t, d) with t = kb*32+l32, d = c*16+hl*8+d0, lid = hl*32+l32:
//    idx = (((bh*64 + kb)*4 + c)*64 + lid)*8 + d0      [one wave frag = 1KB run]
//  V:   elem (b,h, d, t) with d = dc*32+l32, t = kb*32 + ks*16 + hl*8 + k0:
//    idx = ((((bh*64 + kb)*8 + ks*4 + dc*2 + hl))*32 + l32)*8 + k0
// ===========================================================================

// ---------------------------------------------------------------------------
// weight transpose + cast: W[K][N] fp32 -> Wt[N][K] bf16
// ---------------------------------------------------------------------------
struct TArgs {
  const float* src[6];
  bf16* dst[6];
  int K[6];
  int N[6];
};

__global__ __launch_bounds__(256) void transpose_k(TArgs ta) {
  const int mi = blockIdx.z;
  const int K = ta.K[mi], N = ta.N[mi];
  const int nt = N / 32;
  const int bx = blockIdx.x % nt, by = blockIdx.x / nt;
  const int n0 = bx * 32, k0 = by * 32;
  if (k0 >= K) return;
  __shared__ float t[32][33];
  const float* __restrict__ W = ta.src[mi];
  bf16* __restrict__ Wt = ta.dst[mi];
  const int tx = threadIdx.x & 31, ty = threadIdx.x >> 5;
#pragma unroll
  for (int i = 0; i < 4; ++i) {
    int kk = ty + i * 8;
    t[tx][kk] = W[(size_t)(k0 + kk) * N + n0 + tx];
  }
  __syncthreads();
#pragma unroll
  for (int i = 0; i < 4; ++i) {
    int nn = ty + i * 8;
    Wt[(size_t)(n0 + nn) * K + k0 + tx] = __float2bfloat16(t[nn][tx]);
  }
}

// ---------------------------------------------------------------------------
// LayerNorm: one wave per row (768 = 64 lanes x 12 elems), fp32 in -> bf16 out
// ---------------------------------------------------------------------------
__global__ __launch_bounds__(256) void ln_k(const float* __restrict__ x,
                                            const float* __restrict__ g,
                                            const float* __restrict__ b,
                                            bf16* __restrict__ out) {
  const int row = blockIdx.x * 4 + (threadIdx.x >> 6);
  const int lane = threadIdx.x & 63;
  const float* xr = x + (size_t)row * EMBED;
  float4 v[3];
  float s = 0.f;
#pragma unroll
  for (int i = 0; i < 3; ++i) {
    v[i] = *(const float4*)&xr[i * 256 + lane * 4];
    s += v[i].x + v[i].y + v[i].z + v[i].w;
  }
#pragma unroll
  for (int m = 1; m < 64; m <<= 1) s += __shfl_xor(s, m);
  const float mean = s * (1.f / 768.f);
  float ss = 0.f;
#pragma unroll
  for (int i = 0; i < 3; ++i) {
    float dx = v[i].x - mean, dy = v[i].y - mean, dz = v[i].z - mean, dw = v[i].w - mean;
    ss += dx * dx + dy * dy + dz * dz + dw * dw;
  }
#pragma unroll
  for (int m = 1; m < 64; m <<= 1) ss += __shfl_xor(ss, m);
  const float rstd = rsqrtf(ss * (1.f / 768.f) + 1e-5f);
#pragma unroll
  for (int i = 0; i < 3; ++i) {
    float4 g4 = *(const float4*)&g[i * 256 + lane * 4];
    float4 b4 = *(const float4*)&b[i * 256 + lane * 4];
    ushort4v o4;
    o4[0] = f2bf((v[i].x - mean) * rstd * g4.x + b4.x);
    o4[1] = f2bf((v[i].y - mean) * rstd * g4.y + b4.y);
    o4[2] = f2bf((v[i].z - mean) * rstd * g4.z + b4.z);
    o4[3] = f2bf((v[i].w - mean) * rstd * g4.w + b4.w);
    *(ushort4v*)&out[(size_t)row * EMBED + i * 256 + lane * 4] = o4;
  }
}

// ---------------------------------------------------------------------------
// GEMM: C[M][N] = A[M][K] @ Bt[N][K]^T, bf16 inputs, fp32 accum.
// Tile 128xTN; BK=32, triple-buffered LDS + counted vmcnt; chunk-slot XOR
// swizzle both-sides; XCD-chunked 1D block swizzle.
// EPI 0: fused QKV -> FRAGMENT-MAJOR q/k/v buffers (see layout block above)
// EPI 1: outf = resid + C + bias (fp32), LDS-staged float4 coalesced
// EPI 2: outb = gelu(C + bias) via fast-erf, LDS-staged coalesced writes
// ---------------------------------------------------------------------------
template <int EPI, int TN>
__global__ __launch_bounds__(256) void gemm_bt_k(
    const bf16* __restrict__ A, const bf16* __restrict__ Bt,
    const float* __restrict__ bias, const float* __restrict__ bias2,
    const float* __restrict__ bias3, const float* __restrict__ resid,
    float* __restrict__ outf, bf16* __restrict__ outb,
    bf16* __restrict__ outk, bf16* __restrict__ outvt,
    int N, int K) {
  constexpr int MI = (TN == 128) ? 4 : 2;  // 16-row m-frags per wave
  constexpr int SN = (TN == 128) ? 4 : 3;  // gl_lds insts per stage
  constexpr int ABUF = 128 * 32;           // elems per A buffer
  constexpr int BBUF = TN * 32;
  __shared__ __align__(16) bf16 smem[3 * ABUF + 3 * BBUF];
  bf16* Al = smem;
  bf16* Bl = smem + 3 * ABUF;

  const int tid = threadIdx.x;
  const int lane = tid & 63;
  const int w = tid >> 6;
  const int l16 = lane & 15, g = lane >> 4;
  const int wrbase = (TN == 128) ? (w >> 1) * 64 : w * 32;
  const int wcbase = (TN == 128) ? (w & 1) * 64 : 0;

  // XCD-chunked swizzle: consecutive logical blocks -> same XCD
  const int nbx = N / TN;
  const int logical = ((int)blockIdx.x & 7) * ((int)gridDim.x >> 3) + ((int)blockIdx.x >> 3);
  const int m0 = (logical / nbx) * 128, n0 = (logical % nbx) * TN;

  f32x4 acc[MI][4];
#pragma unroll
  for (int i = 0; i < MI; ++i)
#pragma unroll
    for (int j = 0; j < 4; ++j) acc[i][j] = {0.f, 0.f, 0.f, 0.f};

  const int st_r = lane >> 2;                              // row 0..15 in 16-row chunk
  const int st_c = ((lane & 3) ^ ((lane >> 3) & 3)) * 8;   // pre-swizzled source chunk
  const size_t a_base = (size_t)(m0 + w * 32) * K;
  const size_t b_base = (TN == 128) ? (size_t)(n0 + w * 32) * K
                                    : (size_t)(n0 + w * 16) * K;

  auto stage = [&](int bufi, int kt) {
#pragma unroll
    for (int p = 0; p < 2; ++p)
      gl_lds16(A + a_base + (size_t)(p * 16 + st_r) * K + kt + st_c,
               &Al[bufi * ABUF + (w * 32 + p * 16) * 32]);
    if constexpr (TN == 128) {
#pragma unroll
      for (int p = 0; p < 2; ++p)
        gl_lds16(Bt + b_base + (size_t)(p * 16 + st_r) * K + kt + st_c,
                 &Bl[bufi * BBUF + (w * 32 + p * 16) * 32]);
    } else {
      gl_lds16(Bt + b_base + (size_t)st_r * K + kt + st_c, &Bl[bufi * BBUF + (w * 16) * 32]);
    }
  };

  const int nt = K >> 5;
  stage(0, 0);
  stage(1, 32);
  const int sw = (l16 >> 1) & 3;  // read-side swizzle for this lane's rows
  int buf = 0;
  for (int t = 0; t < nt; ++t) {
    if (t < nt - 1) wait_vm<SN>(); else wait_vm<0>();
    block_barrier();  // all waves' stage(t) landed
    if (t + 2 < nt) {
      int nb = buf + 2; if (nb >= 3) nb -= 3;   // (t+2)%3
      stage(nb, (t + 2) * 32);
    }
    short8 af[MI], bfr[4];
#pragma unroll
    for (int i = 0; i < MI; ++i)
      af[i] = *(const short8*)&Al[buf * ABUF + (wrbase + i * 16 + l16) * 32 + (g ^ sw) * 8];
#pragma unroll
    for (int j = 0; j < 4; ++j)
      bfr[j] = *(const short8*)&Bl[buf * BBUF + (wcbase + j * 16 + l16) * 32 + (g ^ sw) * 8];
#pragma unroll
    for (int i = 0; i < MI; ++i)
#pragma unroll
      for (int j = 0; j < 4; ++j) acc[i][j] = mfma16(af[i], bfr[j], acc[i][j]);
    buf = (buf == 2) ? 0 : buf + 1;
  }

  // epilogue: C element (m = crow + i*16 + rr, n = ccol + j*16)
  const int crow = m0 + wrbase + g * 4;
  const int ccol = n0 + wcbase + l16;

  if constexpr (EPI == 0) {
    const int region = n0 / EMBED;  // tile never straddles a 768 boundary
    const float* bp = (region == 0) ? bias : (region == 1) ? bias2 : bias3;
    const int bb2 = m0 >> 11;           // batch (tile never straddles)
    const int kb0 = (m0 & 2047) >> 5;   // 32-token block base (4 per tile)
    if (region < 2) {
      // Q/K: stage swizzled S[128][128], then write FRAGMENT-MAJOR runs.
      const float sc = (region == 0) ? QSCALE : 1.0f;
      bf16* __restrict__ fb = (region == 0) ? outb : outk;
      __syncthreads();               // main-loop LDS reads complete; reuse smem
      bf16* S = smem;                // [128][128], chunk ^= (m&15)
#pragma unroll
      for (int j = 0; j < 4; ++j) {
        const int cn = ccol - region * EMBED + j * 16;
        const float bvv = bp[cn];
        const int nl = wcbase + j * 16 + l16;
#pragma unroll
        for (int i = 0; i < MI; ++i)
#pragma unroll
          for (int rr = 0; rr < 4; ++rr) {
            const int mlcl = wrbase + i * 16 + g * 4 + rr;
            S[mlcl * 128 + (nl ^ ((mlcl & 15) << 3))] =
                __float2bfloat16((acc[i][j][rr] + bvv) * sc);
          }
      }
      __syncthreads();
      const int hbase = (n0 - region * EMBED) >> 6;  // even; tile covers 2 heads
#pragma unroll
      for (int gg = 0; gg < 8; ++gg) {
        const int rid = gg * 256 + tid;      // 0..2047
        const int hp = rid >> 10;            // head within tile
        const int rest2 = rid & 1023;
        const int kbc = rest2 >> 6;          // 0..15
        const int kbl = kbc >> 2, c = kbc & 3;
        const int lid = rest2 & 63;
        const int hl = lid >> 5, l32r = lid & 31;
        const int m_l = kbl * 32 + l32r;
        const int nl = hp * 64 + c * 16 + hl * 8;
        short8 vv = *(const short8*)&S[m_l * 128 + (nl ^ ((m_l & 15) << 3))];
        const size_t fidx =
            ((((size_t)(bb2 * HEADS + hbase + hp) * 64 + kb0 + kbl) * 4 + c) * 64 +
             lid) * 8;
        *(short8*)&fb[fidx] = vv;
      }
    } else {
      // V: stage transposed S[nl][m] (SP=136), then write FRAGMENT-MAJOR runs.
      __syncthreads();               // main-loop LDS reads complete; reuse smem
      constexpr int SP = 136;        // padded stride: 272B rows
      bf16* S = smem;                // 128*136*2 = 34816B
#pragma unroll
      for (int j = 0; j < 4; ++j) {
        const int cn = ccol - 2 * EMBED + j * 16;
        const float bvv = bp[cn];
        const int nl = wcbase + j * 16 + l16;
#pragma unroll
        for (int i = 0; i < MI; ++i) {
          ushort4v pk;
#pragma unroll
          for (int rr = 0; rr < 4; ++rr) pk[rr] = f2bf(acc[i][j][rr] + bvv);
          *(ushort4v*)&S[nl * SP + wrbase + i * 16 + g * 4] = pk;
        }
      }
      __syncthreads();
      const int hbase = (n0 - 2 * EMBED) >> 6;
#pragma unroll
      for (int gg = 0; gg < 8; ++gg) {
        const int rid = gg * 256 + tid;      // 0..2047
        const int hp = rid >> 10;
        const int rest2 = rid & 1023;
        const int kbl = rest2 >> 8;          // 2b
        const int ks = (rest2 >> 7) & 1;
        const int dc = (rest2 >> 6) & 1;
        const int hl = (rest2 >> 5) & 1;
        const int l32r = rest2 & 31;
        const int nl = hp * 64 + dc * 32 + l32r;      // d-col in tile
        const int m_l = kbl * 32 + ks * 16 + hl * 8;  // token base (8 run)
        short8 vv = *(const short8*)&S[nl * SP + m_l];
        const size_t fidx =
            ((((size_t)(bb2 * HEADS + hbase + hp) * 64 + kb0 + kbl) * 8 + ks * 4 +
              dc * 2 + hl) * 32 + l32r) * 8;
        *(short8*)&outvt[fidx] = vv;
      }
    }
  } else if constexpr (EPI == 1) {
    // resid + C + bias (fp32): LDS-staged per 64-row chunk, coalesced float4
    constexpr int SW = TN + 4;       // fp32 row stride (pad -> bank spread)
    float* S32 = (float*)smem;
    const int mychunk = w >> 1;
#pragma unroll
    for (int c = 0; c < 2; ++c) {
      __syncthreads();
      if (mychunk == c) {
        const int rbase = wrbase - c * 64;
#pragma unroll
        for (int j = 0; j < 4; ++j) {
          const int nl = wcbase + j * 16 + l16;
          const float bvv = bias[n0 + nl];
#pragma unroll
          for (int i = 0; i < MI; ++i)
#pragma unroll
            for (int rr = 0; rr < 4; ++rr)
              S32[(rbase + i * 16 + g * 4 + rr) * SW + nl] = acc[i][j][rr] + bvv;
        }
      }
      __syncthreads();
      if constexpr (TN == 128) {
#pragma unroll
        for (int p = 0; p < 8; ++p) {
          const int rowc = p * 8 + (tid >> 5);
          const int c4 = (tid & 31) * 4;
          const int m = m0 + c * 64 + rowc;
          float4 rv = *(const float4*)&resid[(size_t)m * N + n0 + c4];
          const float* sp = &S32[rowc * SW + c4];
          float4 ov;
          ov.x = rv.x + sp[0]; ov.y = rv.y + sp[1];
          ov.z = rv.z + sp[2]; ov.w = rv.w + sp[3];
          *(float4*)&outf[(size_t)m * N + n0 + c4] = ov;
        }
      } else {
#pragma unroll
        for (int p = 0; p < 4; ++p) {
          const int rowc = p * 16 + (tid >> 4);
          const int c4 = (tid & 15) * 4;
          const int m = m0 + c * 64 + rowc;
          float4 rv = *(const float4*)&resid[(size_t)m * N + n0 + c4];
          const float* sp = &S32[rowc * SW + c4];
          float4 ov;
          ov.x = rv.x + sp[0]; ov.y = rv.y + sp[1];
          ov.z = rv.z + sp[2]; ov.w = rv.w + sp[3];
          *(float4*)&outf[(size_t)m * N + n0 + c4] = ov;
        }
      }
    }
  } else {  // EPI == 2: gelu (fast erf) -> bf16, LDS-staged coalesced writes
    __syncthreads();
    bf16* S = smem;                  // [128][128], chunk ^= (m&15)
#pragma unroll
    for (int j = 0; j < 4; ++j) {
      const int cn = ccol + j * 16;
      const float bvv = bias[cn];
      const int nl = wcbase + j * 16 + l16;
#pragma unroll
      for (int i = 0; i < MI; ++i)
#pragma unroll
        for (int rr = 0; rr < 4; ++rr) {
          const int mlcl = wrbase + i * 16 + g * 4 + rr;
          S[mlcl * 128 + (nl ^ ((mlcl & 15) << 3))] =
              __float2bfloat16(gelu_f(acc[i][j][rr] + bvv));
        }
    }
    __syncthreads();
#pragma unroll
    for (int pp = 0; pp < 8; ++pp) {
      const int m_l = pp * 16 + (tid >> 4);
      const int c = tid & 15;
      short8 vv = *(const short8*)&S[m_l * 128 + ((c ^ (m_l & 15)) << 3)];
      *(short8*)&outb[(size_t)(m0 + m_l) * N + n0 + c * 8] = vv;
    }
  }
}

// ---------------------------------------------------------------------------
// Flash attention v12: = v11 (fragment-major direct-from-L2, no LDS, no
// barriers, split-KV x2) + SUM-VIA-MFMA: the softmax denominator is computed
// as ones-row . P with one extra mfma32 pair into sacc (reg 0 read at end),
// replacing the 8-add VALU tree AND the cross-lane shfl on the critical path.
// ---------------------------------------------------------------------------
__global__ __launch_bounds__(256, 4) void flash12_k(const bf16* __restrict__ qfb,
                                                    const bf16* __restrict__ kfb,
                                                    const bf16* __restrict__ vfb,
                                                    bf16* __restrict__ po,
                                                    float2* __restrict__ ml) {
  const int tid = threadIdx.x, lane = tid & 63;
  const int l32 = lane & 31, hl = lane >> 5;
  const int w = tid >> 6;
  // grid = 1536 1D; logical = qt + 16*(half + 2*(h + 12*b)); chunked XCD swizzle
  const int logical = ((int)blockIdx.x & 7) * 192 + ((int)blockIdx.x >> 3);
  const int qt = logical & 15;
  const int rest = logical >> 4;   // 0..95
  const int half = rest & 1;
  const int hb = rest >> 1;        // 0..47
  const int h = hb % HEADS, b = hb / HEADS;
  const int qbi = qt * 4 + w;      // q 32-block 0..63
  const int kv0 = half * (TT / 2);
  const size_t bh = (size_t)(b * HEADS + h);

  // ones A-fragment for the sum MFMA (all 8 elems = bf16 1.0)
  short8 ones;
#pragma unroll
  for (int i = 0; i < 8; ++i) ones[i] = (short)0x3F80;

  // Q fragments: one coalesced load per c
  short8 qf[4];
  {
    const bf16* qp = qfb + ((bh * 64 + qbi) * 4) * 512 + lane * 8;
#pragma unroll
    for (int c = 0; c < 4; ++c) qf[c] = *(const short8*)&qp[c * 512];
  }
  const bf16* __restrict__ kbb = kfb + bh * 64 * 2048;
  const bf16* __restrict__ vbb = vfb + bh * 64 * 2048;

  f32x16 oacc0, oacc1, sacc;
#pragma unroll
  for (int i = 0; i < 16; ++i) { oacc0[i] = 0.f; oacc1[i] = 0.f; sacc[i] = 0.f; }
  float mrun = -1.0e30f;

  auto subtile = [&](int kvabs) {
    const int kb = kvabs >> 5;
    const bf16* kp = kbb + (size_t)kb * 2048 + lane * 8;
    short8 kf[4];
#pragma unroll
    for (int c = 0; c < 4; ++c) kf[c] = *(const short8*)&kp[c * 512];

    f32x16 s;
#pragma unroll
    for (int i = 0; i < 16; ++i) s[i] = 0.f;
    __builtin_amdgcn_s_setprio(1);
#pragma unroll
    for (int c = 0; c < 4; ++c) s = mfma32(kf[c], qf[c], s);
    __builtin_amdgcn_s_setprio(0);

    // row max: max3-fusable triples
    float m0 = fmaxf(fmaxf(s[0], s[1]), s[2]);
    float m1 = fmaxf(fmaxf(s[3], s[4]), s[5]);
    float m2 = fmaxf(fmaxf(s[6], s[7]), s[8]);
    float m3 = fmaxf(fmaxf(s[9], s[10]), s[11]);
    float m4 = fmaxf(fmaxf(s[12], s[13]), s[14]);
    float mx = fmaxf(fmaxf(fmaxf(m0, m1), fmaxf(m2, m3)), fmaxf(m4, s[15]));
    mx = fmaxf(mx, __shfl_xor(mx, 32));

    if (!__all(mx <= mrun + DEFER_THR)) {  // defer-max (T13), log2 units
      const float mn = fmaxf(mrun, mx);
      const float al = fexp2(mrun - mn);
      sacc[0] *= al;                        // only reg 0 is read at the end
#pragma unroll
      for (int i = 0; i < 16; ++i) { oacc0[i] *= al; oacc1[i] *= al; }
      mrun = mn;
    }

    // P in place of S
#pragma unroll
    for (int i = 0; i < 16; ++i) s[i] = fexp2(s[i] - mrun);

    // pack P -> bf16 k-frag layout (T12)
    union { unsigned u[4]; short8 s8; } pa0, pa1;
    {
      unsigned U = cvtpk(s[0], s[1]), V = cvtpk(s[4], s[5]);
      pl32swap(V, U); pa0.u[0] = U; pa0.u[2] = V;
      unsigned U1 = cvtpk(s[2], s[3]), V1 = cvtpk(s[6], s[7]);
      pl32swap(V1, U1); pa0.u[1] = U1; pa0.u[3] = V1;
    }
    {
      unsigned U = cvtpk(s[8], s[9]), V = cvtpk(s[12], s[13]);
      pl32swap(V, U); pa1.u[0] = U; pa1.u[2] = V;
      unsigned U1 = cvtpk(s[10], s[11]), V1 = cvtpk(s[14], s[15]);
      pl32swap(V1, U1); pa1.u[1] = U1; pa1.u[3] = V1;
    }

    // V fragments: coalesced loads (hl folded into lane)
    const bf16* vp = vbb + (size_t)kb * 2048 + lane * 8;
    short8 vf[4];
#pragma unroll
    for (int ks = 0; ks < 2; ++ks)
#pragma unroll
      for (int dc = 0; dc < 2; ++dc)
        vf[ks * 2 + dc] = *(const short8*)&vp[(ks * 4 + dc * 2) * 256];

    __builtin_amdgcn_s_setprio(1);
    oacc0 = mfma32(vf[0], pa0.s8, oacc0);  // ks0, d 0..31
    oacc0 = mfma32(vf[2], pa1.s8, oacc0);  // ks1, d 0..31
    oacc1 = mfma32(vf[1], pa0.s8, oacc1);  // ks0, d 32..63
    oacc1 = mfma32(vf[3], pa1.s8, oacc1);  // ks1, d 32..63
    sacc = mfma32(ones, pa0.s8, sacc);     // row-sum via MFMA (all regs equal)
    sacc = mfma32(ones, pa1.s8, sacc);
    __builtin_amdgcn_s_setprio(0);
  };

  const int NT = (TT / 2) / 64;  // 16 tiles of 64 kv
  for (int t = 0; t < NT; ++t) {
    const int base = kv0 + t * 64;
    subtile(base);
    subtile(base + 32);
  }

  // epilogue: unnormalized O^T partial (bf16) + (m,l).
  // O^T C-layout: col=q=l32 (lane-local), row=d=(r&3)+8*(r>>2)+4*hl
  const int q0 = qbi * 32;
  bf16* pp = po + ((size_t)((half * BB + b) * HEADS + h) * TT + q0 + l32) * 64;
#pragma unroll
  for (int a = 0; a < 4; ++a) {
    ushort4v pk4;
#pragma unroll
    for (int bb = 0; bb < 4; ++bb) pk4[bb] = f2bf(oacc0[a * 4 + bb]);
    *(ushort4v*)&pp[a * 8 + hl * 4] = pk4;
#pragma unroll
    for (int bb = 0; bb < 4; ++bb) pk4[bb] = f2bf(oacc1[a * 4 + bb]);
    *(ushort4v*)&pp[32 + a * 8 + hl * 4] = pk4;
  }
  if (hl == 0) {
    float2 v2; v2.x = mrun; v2.y = sacc[0];
    ml[(size_t)((half * BB + b) * HEADS + h) * TT + q0 + l32] = v2;
  }
}

// ---------------------------------------------------------------------------
// combine_k: merge the two KV-half partials.
// ---------------------------------------------------------------------------
__global__ __launch_bounds__(256) void combine_k(const bf16* __restrict__ po,
                                                 const float2* __restrict__ ml,
                                                 bf16* __restrict__ o) {
  const int row = blockIdx.x * 4 + (threadIdx.x >> 6);  // (b*H+h)*T + t
  const int lane = threadIdx.x & 63;
  const size_t NR = (size_t)BB * HEADS * TT;
  const float2 a = ml[row];
  const float2 c = ml[NR + row];
  const float M = fmaxf(a.x, c.x);
  const float w0 = fexp2(a.x - M), w1 = fexp2(c.x - M);
  const float inv = 1.f / (w0 * a.y + w1 * c.y);
  const float o0 = __bfloat162float(po[(size_t)row * 64 + lane]);
  const float o1 = __bfloat162float(po[NR * 64 + (size_t)row * 64 + lane]);
  const float val = (w0 * o0 + w1 * o1) * inv;
  const int b = row / (HEADS * TT);
  const int rem = row % (HEADS * TT);
  const int h = rem / TT, t = rem % TT;
  o[((size_t)(b * TT + t)) * EMBED + h * HDIM + lane] = __float2bfloat16(val);
}

// ---------------------------------------------------------------------------
extern "C" void kernel_launch(void* const* d_in, const int* in_sizes, int n_in,
                              void* d_out, int out_size, void* d_ws,
                              size_t ws_size, hipStream_t stream) {
  const float* x = (const float*)d_in[0];
  const float* ln1g = (const float*)d_in[1];
  const float* ln1b = (const float*)d_in[2];
  const float* wq = (const float*)d_in[3];
  const float* bq = (const float*)d_in[4];
  const float* wk = (const float*)d_in[5];
  const float* bk = (const float*)d_in[6];
  const float* wv = (const float*)d_in[7];
  const float* bv = (const float*)d_in[8];
  const float* wo = (const float*)d_in[9];
  const float* bo = (const float*)d_in[10];
  const float* ln2g = (const float*)d_in[11];
  const float* ln2b = (const float*)d_in[12];
  const float* w1 = (const float*)d_in[13];
  const float* b1 = (const float*)d_in[14];
  const float* w2 = (const float*)d_in[15];
  const float* b2 = (const float*)d_in[16];
  float* out = (float*)d_out;

  char* ws = (char*)d_ws;
  size_t off = 0;
  auto alloc = [&](size_t bytes) {
    char* p = ws + off;
    off += (bytes + 255) & ~(size_t)255;
    return p;
  };
  bf16* wqkv_t = (bf16*)alloc((size_t)2304 * 768 * 2);
  bf16* wo_t = (bf16*)alloc((size_t)768 * 768 * 2);
  bf16* w1_t = (bf16*)alloc((size_t)3072 * 768 * 2);
  bf16* w2_t = (bf16*)alloc((size_t)768 * 3072 * 2);
  bf16* h = (bf16*)alloc((size_t)MTOK * EMBED * 2);
  // qb/kb/vtb/ob dead once o-proj runs; h1 overlays them
  char* qkvo = alloc((size_t)MTOK * EMBED * 2 * 4);
  bf16* qb = (bf16*)qkvo;                       // fragment-major Q
  bf16* kb = qb + (size_t)MTOK * EMBED;         // fragment-major K
  bf16* vtb = kb + (size_t)MTOK * EMBED;        // fragment-major V
  bf16* ob = vtb + (size_t)MTOK * EMBED;
  bf16* h1 = (bf16*)qkvo;  // [MTOK][3072] bf16, overlays q/k/vt/o
  float* x1 = (float*)alloc((size_t)MTOK * EMBED * 4);
  (void)ws_size;
  // Overlays (lifetime-safe): po (24MB) in x1's region; ml (1.5MB) in h's.
  bf16* po = (bf16*)x1;
  float2* mlb = (float2*)h;

  TArgs ta;
  ta.src[0] = wq; ta.dst[0] = wqkv_t;                  ta.K[0] = 768;  ta.N[0] = 768;
  ta.src[1] = wk; ta.dst[1] = wqkv_t + 768 * 768;      ta.K[1] = 768;  ta.N[1] = 768;
  ta.src[2] = wv; ta.dst[2] = wqkv_t + 2 * 768 * 768;  ta.K[2] = 768;  ta.N[2] = 768;
  ta.src[3] = wo; ta.dst[3] = wo_t;                    ta.K[3] = 768;  ta.N[3] = 768;
  ta.src[4] = w1; ta.dst[4] = w1_t;                    ta.K[4] = 768;  ta.N[4] = 3072;
  ta.src[5] = w2; ta.dst[5] = w2_t;                    ta.K[5] = 3072; ta.N[5] = 768;

  transpose_k<<<dim3(2304, 1, 6), dim3(256), 0, stream>>>(ta);
  ln_k<<<dim3(MTOK / 4), dim3(256), 0, stream>>>(x, ln1g, ln1b, h);
  gemm_bt_k<0, 128><<<dim3((2304 / 128) * (MTOK / 128)), dim3(256), 0, stream>>>(
      h, wqkv_t, bq, bk, bv, nullptr, nullptr, qb, kb, vtb, 2304, 768);
  flash12_k<<<dim3(16 * HEADS * BB * 2), dim3(256), 0, stream>>>(qb, kb, vtb, po, mlb);
  combine_k<<<dim3(BB * HEADS * TT / 4), dim3(256), 0, stream>>>(po, mlb, ob);
  gemm_bt_k<1, 64><<<dim3((768 / 64) * (MTOK / 128)), dim3(256), 0, stream>>>(
      ob, wo_t, bo, nullptr, nullptr, x, x1, nullptr, nullptr, nullptr, 768, 768);
  ln_k<<<dim3(MTOK / 4), dim3(256), 0, stream>>>(x1, ln2g, ln2b, h);
  gemm_bt_k<2, 128><<<dim3((3072 / 128) * (MTOK / 128)), dim3(256), 0, stream>>>(
      h, w1_t, b1, nullptr, nullptr, nullptr, nullptr, h1, nullptr, nullptr, 3072, 768);
  gemm_bt_k<1, 128><<<dim3((768 / 128) * (MTOK / 128)), dim3(256), 0, stream>>>(
      h1, w2_t, b2, nullptr, nullptr, x1, out, nullptr, nullptr, nullptr, 768, 3072);
}

// Round 17
// 276.209 us; speedup vs baseline: 1.0618x; 1.0618x over previous
//
#include <hip/hip_runtime.h>
#include <hip/hip_bf16.h>

#define EMBED 768
#define FFNDIM 3072
#define HEADS 12
#define HDIM  64
#define BB    4
#define TT    2048
#define MTOK  (BB*TT)   // 8192 tokens

typedef __hip_bfloat16 bf16;
typedef __attribute__((ext_vector_type(8))) short short8;
typedef __attribute__((ext_vector_type(4))) float f32x4;
typedef __attribute__((ext_vector_type(16))) float f32x16;
typedef __attribute__((ext_vector_type(4))) unsigned short ushort4v;

__device__ __forceinline__ f32x4 mfma16(short8 a, short8 b, f32x4 c) {
  return __builtin_amdgcn_mfma_f32_16x16x32_bf16(a, b, c, 0, 0, 0);
}
__device__ __forceinline__ f32x16 mfma32(short8 a, short8 b, f32x16 c) {
  return __builtin_amdgcn_mfma_f32_32x32x16_bf16(a, b, c, 0, 0, 0);
}

__device__ __forceinline__ unsigned short f2bf(float f) {
  union { float f; unsigned int u; } v; v.f = f;
  unsigned int u = v.u;
  return (unsigned short)((u + 0x7fffu + ((u >> 16) & 1u)) >> 16);
}

// 2^x via the native transcendental
__device__ __forceinline__ float fexp2(float x) {
#if __has_builtin(__builtin_amdgcn_exp2f)
  return __builtin_amdgcn_exp2f(x);
#else
  return exp2f(x);
#endif
}

// exact-GELU via A&S 7.1.26 erf (|err| <= 1.5e-7, far below bf16 ulp)
__device__ __forceinline__ float gelu_f(float v) {
  const float ax = fabsf(v) * 0.70710678118f;   // |v|/sqrt(2)
  const float t = __builtin_amdgcn_rcpf(1.f + 0.3275911f * ax);
  float p = 1.061405429f;
  p = p * t - 1.453152027f;
  p = p * t + 1.421413741f;
  p = p * t - 0.284496736f;
  p = p * t + 0.254829592f;
  p = p * t;
  const float e = fexp2(-ax * ax * 1.4426950408889634f);  // exp(-x^2)
  float er = 1.f - p * e;
  er = (v < 0.f) ? -er : er;
  return 0.5f * v * (1.f + er);
}

// v_cvt_pk_bf16_f32: pack two f32 -> two bf16 in one dword (lo, hi), RNE
__device__ __forceinline__ unsigned cvtpk(float lo, float hi) {
  unsigned r;
  asm("v_cvt_pk_bf16_f32 %0, %1, %2" : "=v"(r) : "v"(lo), "v"(hi));
  return r;
}
// v_permlane32_swap_b32: vdst[0:31]<->vsrc[32:63] swap
__device__ __forceinline__ void pl32swap(unsigned& vdst, unsigned& vsrc) {
  asm("v_permlane32_swap_b32 %0, %1" : "+v"(vdst), "+v"(vsrc));
}

// async global->LDS, 16B per lane; lds dest is wave-uniform base + lane*16
__device__ __forceinline__ void gl_lds16(const void* g, void* l) {
  __builtin_amdgcn_global_load_lds((const __attribute__((address_space(1))) void*)g,
                                   (__attribute__((address_space(3))) void*)l, 16, 0, 0);
}

// counted vmcnt wait (immediate), fenced so following ops can't hoist above it
template <int N>
__device__ __forceinline__ void wait_vm() {
  asm volatile("s_waitcnt vmcnt(%0)" :: "i"(N) : "memory");
  __builtin_amdgcn_sched_barrier(0);
}
__device__ __forceinline__ void block_barrier() {
  __builtin_amdgcn_sched_barrier(0);
  __builtin_amdgcn_s_barrier();
  __builtin_amdgcn_sched_barrier(0);
}

// q pre-scale: (1/sqrt(64)) * log2(e), so softmax runs in exp2 domain
#define QSCALE 0.18033688011112042f
#define DEFER_THR 11.54f   // 8 nats in log2 units

// ===========================================================================
// FRAGMENT-MAJOR layouts (producer = QKV GEMM epilogue, consumer = flash):
//  Q/K: elem (b,h, t, d) with t = kb*32+l32, d = c*16+hl*8+d0, lid = hl*32+l32:
//    idx = (((bh*64 + kb)*4 + c)*64 + lid)*8 + d0      [one wave frag = 1KB run]
//  V:   elem (b,h, d, t) with d = dc*32+l32, t = kb*32 + ks*16 + hl*8 + k0:
//    idx = ((((bh*64 + kb)*8 + ks*4 + dc*2 + hl))*32 + l32)*8 + k0
// ===========================================================================

// ---------------------------------------------------------------------------
// weight transpose + cast: W[K][N] fp32 -> Wt[N][K] bf16
// ---------------------------------------------------------------------------
struct TArgs {
  const float* src[6];
  bf16* dst[6];
  int K[6];
  int N[6];
};

__global__ __launch_bounds__(256) void transpose_k(TArgs ta) {
  const int mi = blockIdx.z;
  const int K = ta.K[mi], N = ta.N[mi];
  const int nt = N / 32;
  const int bx = blockIdx.x % nt, by = blockIdx.x / nt;
  const int n0 = bx * 32, k0 = by * 32;
  if (k0 >= K) return;
  __shared__ float t[32][33];
  const float* __restrict__ W = ta.src[mi];
  bf16* __restrict__ Wt = ta.dst[mi];
  const int tx = threadIdx.x & 31, ty = threadIdx.x >> 5;
#pragma unroll
  for (int i = 0; i < 4; ++i) {
    int kk = ty + i * 8;
    t[tx][kk] = W[(size_t)(k0 + kk) * N + n0 + tx];
  }
  __syncthreads();
#pragma unroll
  for (int i = 0; i < 4; ++i) {
    int nn = ty + i * 8;
    Wt[(size_t)(n0 + nn) * K + k0 + tx] = __float2bfloat16(t[nn][tx]);
  }
}

// ---------------------------------------------------------------------------
// LayerNorm: one wave per row (768 = 64 lanes x 12 elems), fp32 in -> bf16 out
// ---------------------------------------------------------------------------
__global__ __launch_bounds__(256) void ln_k(const float* __restrict__ x,
                                            const float* __restrict__ g,
                                            const float* __restrict__ b,
                                            bf16* __restrict__ out) {
  const int row = blockIdx.x * 4 + (threadIdx.x >> 6);
  const int lane = threadIdx.x & 63;
  const float* xr = x + (size_t)row * EMBED;
  float4 v[3];
  float s = 0.f;
#pragma unroll
  for (int i = 0; i < 3; ++i) {
    v[i] = *(const float4*)&xr[i * 256 + lane * 4];
    s += v[i].x + v[i].y + v[i].z + v[i].w;
  }
#pragma unroll
  for (int m = 1; m < 64; m <<= 1) s += __shfl_xor(s, m);
  const float mean = s * (1.f / 768.f);
  float ss = 0.f;
#pragma unroll
  for (int i = 0; i < 3; ++i) {
    float dx = v[i].x - mean, dy = v[i].y - mean, dz = v[i].z - mean, dw = v[i].w - mean;
    ss += dx * dx + dy * dy + dz * dz + dw * dw;
  }
#pragma unroll
  for (int m = 1; m < 64; m <<= 1) ss += __shfl_xor(ss, m);
  const float rstd = rsqrtf(ss * (1.f / 768.f) + 1e-5f);
#pragma unroll
  for (int i = 0; i < 3; ++i) {
    float4 g4 = *(const float4*)&g[i * 256 + lane * 4];
    float4 b4 = *(const float4*)&b[i * 256 + lane * 4];
    ushort4v o4;
    o4[0] = f2bf((v[i].x - mean) * rstd * g4.x + b4.x);
    o4[1] = f2bf((v[i].y - mean) * rstd * g4.y + b4.y);
    o4[2] = f2bf((v[i].z - mean) * rstd * g4.z + b4.z);
    o4[3] = f2bf((v[i].w - mean) * rstd * g4.w + b4.w);
    *(ushort4v*)&out[(size_t)row * EMBED + i * 256 + lane * 4] = o4;
  }
}

// ---------------------------------------------------------------------------
// GEMM: C[M][N] = A[M][K] @ Bt[N][K]^T, bf16 inputs, fp32 accum.
// Tile 128xTN; BK=32, triple-buffered LDS + counted vmcnt; chunk-slot XOR
// swizzle both-sides; XCD-chunked 1D block swizzle.
// EPI 0: fused QKV -> FRAGMENT-MAJOR q/k/v buffers (see layout block above)
// EPI 1: outf = resid + C + bias (fp32), LDS-staged float4 coalesced
// EPI 2: outb = gelu(C + bias) via fast-erf, LDS-staged coalesced writes
// ---------------------------------------------------------------------------
template <int EPI, int TN>
__global__ __launch_bounds__(256) void gemm_bt_k(
    const bf16* __restrict__ A, const bf16* __restrict__ Bt,
    const float* __restrict__ bias, const float* __restrict__ bias2,
    const float* __restrict__ bias3, const float* __restrict__ resid,
    float* __restrict__ outf, bf16* __restrict__ outb,
    bf16* __restrict__ outk, bf16* __restrict__ outvt,
    int N, int K) {
  constexpr int MI = (TN == 128) ? 4 : 2;  // 16-row m-frags per wave
  constexpr int SN = (TN == 128) ? 4 : 3;  // gl_lds insts per stage
  constexpr int ABUF = 128 * 32;           // elems per A buffer
  constexpr int BBUF = TN * 32;
  __shared__ __align__(16) bf16 smem[3 * ABUF + 3 * BBUF];
  bf16* Al = smem;
  bf16* Bl = smem + 3 * ABUF;

  const int tid = threadIdx.x;
  const int lane = tid & 63;
  const int w = tid >> 6;
  const int l16 = lane & 15, g = lane >> 4;
  const int wrbase = (TN == 128) ? (w >> 1) * 64 : w * 32;
  const int wcbase = (TN == 128) ? (w & 1) * 64 : 0;

  // XCD-chunked swizzle: consecutive logical blocks -> same XCD
  const int nbx = N / TN;
  const int logical = ((int)blockIdx.x & 7) * ((int)gridDim.x >> 3) + ((int)blockIdx.x >> 3);
  const int m0 = (logical / nbx) * 128, n0 = (logical % nbx) * TN;

  f32x4 acc[MI][4];
#pragma unroll
  for (int i = 0; i < MI; ++i)
#pragma unroll
    for (int j = 0; j < 4; ++j) acc[i][j] = {0.f, 0.f, 0.f, 0.f};

  const int st_r = lane >> 2;                              // row 0..15 in 16-row chunk
  const int st_c = ((lane & 3) ^ ((lane >> 3) & 3)) * 8;   // pre-swizzled source chunk
  const size_t a_base = (size_t)(m0 + w * 32) * K;
  const size_t b_base = (TN == 128) ? (size_t)(n0 + w * 32) * K
                                    : (size_t)(n0 + w * 16) * K;

  auto stage = [&](int bufi, int kt) {
#pragma unroll
    for (int p = 0; p < 2; ++p)
      gl_lds16(A + a_base + (size_t)(p * 16 + st_r) * K + kt + st_c,
               &Al[bufi * ABUF + (w * 32 + p * 16) * 32]);
    if constexpr (TN == 128) {
#pragma unroll
      for (int p = 0; p < 2; ++p)
        gl_lds16(Bt + b_base + (size_t)(p * 16 + st_r) * K + kt + st_c,
                 &Bl[bufi * BBUF + (w * 32 + p * 16) * 32]);
    } else {
      gl_lds16(Bt + b_base + (size_t)st_r * K + kt + st_c, &Bl[bufi * BBUF + (w * 16) * 32]);
    }
  };

  const int nt = K >> 5;
  stage(0, 0);
  stage(1, 32);
  const int sw = (l16 >> 1) & 3;  // read-side swizzle for this lane's rows
  int buf = 0;
  for (int t = 0; t < nt; ++t) {
    if (t < nt - 1) wait_vm<SN>(); else wait_vm<0>();
    block_barrier();  // all waves' stage(t) landed
    if (t + 2 < nt) {
      int nb = buf + 2; if (nb >= 3) nb -= 3;   // (t+2)%3
      stage(nb, (t + 2) * 32);
    }
    short8 af[MI], bfr[4];
#pragma unroll
    for (int i = 0; i < MI; ++i)
      af[i] = *(const short8*)&Al[buf * ABUF + (wrbase + i * 16 + l16) * 32 + (g ^ sw) * 8];
#pragma unroll
    for (int j = 0; j < 4; ++j)
      bfr[j] = *(const short8*)&Bl[buf * BBUF + (wcbase + j * 16 + l16) * 32 + (g ^ sw) * 8];
#pragma unroll
    for (int i = 0; i < MI; ++i)
#pragma unroll
      for (int j = 0; j < 4; ++j) acc[i][j] = mfma16(af[i], bfr[j], acc[i][j]);
    buf = (buf == 2) ? 0 : buf + 1;
  }

  // epilogue: C element (m = crow + i*16 + rr, n = ccol + j*16)
  const int crow = m0 + wrbase + g * 4;
  const int ccol = n0 + wcbase + l16;

  if constexpr (EPI == 0) {
    const int region = n0 / EMBED;  // tile never straddles a 768 boundary
    const float* bp = (region == 0) ? bias : (region == 1) ? bias2 : bias3;
    const int bb2 = m0 >> 11;           // batch (tile never straddles)
    const int kb0 = (m0 & 2047) >> 5;   // 32-token block base (4 per tile)
    if (region < 2) {
      // Q/K: stage swizzled S[128][128], then write FRAGMENT-MAJOR runs.
      const float sc = (region == 0) ? QSCALE : 1.0f;
      bf16* __restrict__ fb = (region == 0) ? outb : outk;
      __syncthreads();               // main-loop LDS reads complete; reuse smem
      bf16* S = smem;                // [128][128], chunk ^= (m&15)
#pragma unroll
      for (int j = 0; j < 4; ++j) {
        const int cn = ccol - region * EMBED + j * 16;
        const float bvv = bp[cn];
        const int nl = wcbase + j * 16 + l16;
#pragma unroll
        for (int i = 0; i < MI; ++i)
#pragma unroll
          for (int rr = 0; rr < 4; ++rr) {
            const int mlcl = wrbase + i * 16 + g * 4 + rr;
            S[mlcl * 128 + (nl ^ ((mlcl & 15) << 3))] =
                __float2bfloat16((acc[i][j][rr] + bvv) * sc);
          }
      }
      __syncthreads();
      const int hbase = (n0 - region * EMBED) >> 6;  // even; tile covers 2 heads
#pragma unroll
      for (int gg = 0; gg < 8; ++gg) {
        const int rid = gg * 256 + tid;      // 0..2047
        const int hp = rid >> 10;            // head within tile
        const int rest2 = rid & 1023;
        const int kbc = rest2 >> 6;          // 0..15
        const int kbl = kbc >> 2, c = kbc & 3;
        const int lid = rest2 & 63;
        const int hl = lid >> 5, l32r = lid & 31;
        const int m_l = kbl * 32 + l32r;
        const int nl = hp * 64 + c * 16 + hl * 8;
        short8 vv = *(const short8*)&S[m_l * 128 + (nl ^ ((m_l & 15) << 3))];
        const size_t fidx =
            ((((size_t)(bb2 * HEADS + hbase + hp) * 64 + kb0 + kbl) * 4 + c) * 64 +
             lid) * 8;
        *(short8*)&fb[fidx] = vv;
      }
    } else {
      // V: stage transposed S[nl][m] (SP=136), then write FRAGMENT-MAJOR runs.
      __syncthreads();               // main-loop LDS reads complete; reuse smem
      constexpr int SP = 136;        // padded stride: 272B rows
      bf16* S = smem;                // 128*136*2 = 34816B
#pragma unroll
      for (int j = 0; j < 4; ++j) {
        const int cn = ccol - 2 * EMBED + j * 16;
        const float bvv = bp[cn];
        const int nl = wcbase + j * 16 + l16;
#pragma unroll
        for (int i = 0; i < MI; ++i) {
          ushort4v pk;
#pragma unroll
          for (int rr = 0; rr < 4; ++rr) pk[rr] = f2bf(acc[i][j][rr] + bvv);
          *(ushort4v*)&S[nl * SP + wrbase + i * 16 + g * 4] = pk;
        }
      }
      __syncthreads();
      const int hbase = (n0 - 2 * EMBED) >> 6;
#pragma unroll
      for (int gg = 0; gg < 8; ++gg) {
        const int rid = gg * 256 + tid;      // 0..2047
        const int hp = rid >> 10;
        const int rest2 = rid & 1023;
        const int kbl = rest2 >> 8;          // 2b
        const int ks = (rest2 >> 7) & 1;
        const int dc = (rest2 >> 6) & 1;
        const int hl = (rest2 >> 5) & 1;
        const int l32r = rest2 & 31;
        const int nl = hp * 64 + dc * 32 + l32r;      // d-col in tile
        const int m_l = kbl * 32 + ks * 16 + hl * 8;  // token base (8 run)
        short8 vv = *(const short8*)&S[nl * SP + m_l];
        const size_t fidx =
            ((((size_t)(bb2 * HEADS + hbase + hp) * 64 + kb0 + kbl) * 8 + ks * 4 +
              dc * 2 + hl) * 32 + l32r) * 8;
        *(short8*)&outvt[fidx] = vv;
      }
    }
  } else if constexpr (EPI == 1) {
    // resid + C + bias (fp32): LDS-staged per 64-row chunk, coalesced float4
    constexpr int SW = TN + 4;       // fp32 row stride (pad -> bank spread)
    float* S32 = (float*)smem;
    const int mychunk = w >> 1;
#pragma unroll
    for (int c = 0; c < 2; ++c) {
      __syncthreads();
      if (mychunk == c) {
        const int rbase = wrbase - c * 64;
#pragma unroll
        for (int j = 0; j < 4; ++j) {
          const int nl = wcbase + j * 16 + l16;
          const float bvv = bias[n0 + nl];
#pragma unroll
          for (int i = 0; i < MI; ++i)
#pragma unroll
            for (int rr = 0; rr < 4; ++rr)
              S32[(rbase + i * 16 + g * 4 + rr) * SW + nl] = acc[i][j][rr] + bvv;
        }
      }
      __syncthreads();
      if constexpr (TN == 128) {
#pragma unroll
        for (int p = 0; p < 8; ++p) {
          const int rowc = p * 8 + (tid >> 5);
          const int c4 = (tid & 31) * 4;
          const int m = m0 + c * 64 + rowc;
          float4 rv = *(const float4*)&resid[(size_t)m * N + n0 + c4];
          const float* sp = &S32[rowc * SW + c4];
          float4 ov;
          ov.x = rv.x + sp[0]; ov.y = rv.y + sp[1];
          ov.z = rv.z + sp[2]; ov.w = rv.w + sp[3];
          *(float4*)&outf[(size_t)m * N + n0 + c4] = ov;
        }
      } else {
#pragma unroll
        for (int p = 0; p < 4; ++p) {
          const int rowc = p * 16 + (tid >> 4);
          const int c4 = (tid & 15) * 4;
          const int m = m0 + c * 64 + rowc;
          float4 rv = *(const float4*)&resid[(size_t)m * N + n0 + c4];
          const float* sp = &S32[rowc * SW + c4];
          float4 ov;
          ov.x = rv.x + sp[0]; ov.y = rv.y + sp[1];
          ov.z = rv.z + sp[2]; ov.w = rv.w + sp[3];
          *(float4*)&outf[(size_t)m * N + n0 + c4] = ov;
        }
      }
    }
  } else {  // EPI == 2: gelu (fast erf) -> bf16, LDS-staged coalesced writes
    __syncthreads();
    bf16* S = smem;                  // [128][128], chunk ^= (m&15)
#pragma unroll
    for (int j = 0; j < 4; ++j) {
      const int cn = ccol + j * 16;
      const float bvv = bias[cn];
      const int nl = wcbase + j * 16 + l16;
#pragma unroll
      for (int i = 0; i < MI; ++i)
#pragma unroll
        for (int rr = 0; rr < 4; ++rr) {
          const int mlcl = wrbase + i * 16 + g * 4 + rr;
          S[mlcl * 128 + (nl ^ ((mlcl & 15) << 3))] =
              __float2bfloat16(gelu_f(acc[i][j][rr] + bvv));
        }
    }
    __syncthreads();
#pragma unroll
    for (int pp = 0; pp < 8; ++pp) {
      const int m_l = pp * 16 + (tid >> 4);
      const int c = tid & 15;
      short8 vv = *(const short8*)&S[m_l * 128 + ((c ^ (m_l & 15)) << 3)];
      *(short8*)&outb[(size_t)(m0 + m_l) * N + n0 + c * 8] = vv;
    }
  }
}

// ---------------------------------------------------------------------------
// Flash attention v13: fragment-major direct-from-L2, NO split-KV. One block
// covers the full 2048-token KV range (grid 768 = 3 blocks/CU); O normalized
// in-kernel and written directly to [b,t,h,d] — combine pass and 50MB of
// partial traffic deleted. Compute core = flash11 (VALU sum reverted).
// ---------------------------------------------------------------------------
__global__ __launch_bounds__(256, 4) void flash13_k(const bf16* __restrict__ qfb,
                                                    const bf16* __restrict__ kfb,
                                                    const bf16* __restrict__ vfb,
                                                    bf16* __restrict__ o) {
  const int tid = threadIdx.x, lane = tid & 63;
  const int l32 = lane & 31, hl = lane >> 5;
  const int w = tid >> 6;
  // grid = 768 1D; logical = qt + 16*(h + 12*b); chunked XCD swizzle
  const int logical = ((int)blockIdx.x & 7) * 96 + ((int)blockIdx.x >> 3);
  const int qt = logical & 15;
  const int hb = logical >> 4;     // 0..47
  const int h = hb % HEADS, b = hb / HEADS;
  const int qbi = qt * 4 + w;      // q 32-block 0..63
  const size_t bh = (size_t)(b * HEADS + h);

  // Q fragments: one coalesced load per c
  short8 qf[4];
  {
    const bf16* qp = qfb + ((bh * 64 + qbi) * 4) * 512 + lane * 8;
#pragma unroll
    for (int c = 0; c < 4; ++c) qf[c] = *(const short8*)&qp[c * 512];
  }
  const bf16* __restrict__ kbb = kfb + bh * 64 * 2048;
  const bf16* __restrict__ vbb = vfb + bh * 64 * 2048;

  f32x16 oacc0, oacc1;
#pragma unroll
  for (int i = 0; i < 16; ++i) { oacc0[i] = 0.f; oacc1[i] = 0.f; }
  float mrun = -1.0e30f, lrun = 0.f;

  auto subtile = [&](int kb) {
    const bf16* kp = kbb + (size_t)kb * 2048 + lane * 8;
    short8 kf[4];
#pragma unroll
    for (int c = 0; c < 4; ++c) kf[c] = *(const short8*)&kp[c * 512];

    f32x16 s;
#pragma unroll
    for (int i = 0; i < 16; ++i) s[i] = 0.f;
    __builtin_amdgcn_s_setprio(1);
#pragma unroll
    for (int c = 0; c < 4; ++c) s = mfma32(kf[c], qf[c], s);
    __builtin_amdgcn_s_setprio(0);

    // row max: max3-fusable triples
    float m0 = fmaxf(fmaxf(s[0], s[1]), s[2]);
    float m1 = fmaxf(fmaxf(s[3], s[4]), s[5]);
    float m2 = fmaxf(fmaxf(s[6], s[7]), s[8]);
    float m3 = fmaxf(fmaxf(s[9], s[10]), s[11]);
    float m4 = fmaxf(fmaxf(s[12], s[13]), s[14]);
    float mx = fmaxf(fmaxf(fmaxf(m0, m1), fmaxf(m2, m3)), fmaxf(m4, s[15]));
    mx = fmaxf(mx, __shfl_xor(mx, 32));

    if (!__all(mx <= mrun + DEFER_THR)) {  // defer-max (T13), log2 units
      const float mn = fmaxf(mrun, mx);
      const float al = fexp2(mrun - mn);
      lrun *= al;
#pragma unroll
      for (int i = 0; i < 16; ++i) { oacc0[i] *= al; oacc1[i] *= al; }
      mrun = mn;
    }

    // P in place of S
#pragma unroll
    for (int i = 0; i < 16; ++i) s[i] = fexp2(s[i] - mrun);
    float a8[8];
#pragma unroll
    for (int i = 0; i < 8; ++i) a8[i] = s[2 * i] + s[2 * i + 1];
    float ps = ((a8[0] + a8[1]) + (a8[2] + a8[3])) + ((a8[4] + a8[5]) + (a8[6] + a8[7]));
    ps += __shfl_xor(ps, 32);
    lrun += ps;

    // pack P -> bf16 k-frag layout (T12)
    union { unsigned u[4]; short8 s8; } pa0, pa1;
    {
      unsigned U = cvtpk(s[0], s[1]), V = cvtpk(s[4], s[5]);
      pl32swap(V, U); pa0.u[0] = U; pa0.u[2] = V;
      unsigned U1 = cvtpk(s[2], s[3]), V1 = cvtpk(s[6], s[7]);
      pl32swap(V1, U1); pa0.u[1] = U1; pa0.u[3] = V1;
    }
    {
      unsigned U = cvtpk(s[8], s[9]), V = cvtpk(s[12], s[13]);
      pl32swap(V, U); pa1.u[0] = U; pa1.u[2] = V;
      unsigned U1 = cvtpk(s[10], s[11]), V1 = cvtpk(s[14], s[15]);
      pl32swap(V1, U1); pa1.u[1] = U1; pa1.u[3] = V1;
    }

    // V fragments: coalesced loads (hl folded into lane)
    const bf16* vp = vbb + (size_t)kb * 2048 + lane * 8;
    short8 vf[4];
#pragma unroll
    for (int ks = 0; ks < 2; ++ks)
#pragma unroll
      for (int dc = 0; dc < 2; ++dc)
        vf[ks * 2 + dc] = *(const short8*)&vp[(ks * 4 + dc * 2) * 256];

    __builtin_amdgcn_s_setprio(1);
    oacc0 = mfma32(vf[0], pa0.s8, oacc0);  // ks0, d 0..31
    oacc0 = mfma32(vf[2], pa1.s8, oacc0);  // ks1, d 0..31
    oacc1 = mfma32(vf[1], pa0.s8, oacc1);  // ks0, d 32..63
    oacc1 = mfma32(vf[3], pa1.s8, oacc1);  // ks1, d 32..63
    __builtin_amdgcn_s_setprio(0);
  };

  for (int kb = 0; kb < 64; ++kb) subtile(kb);   // full KV range, 32 kv per kb

  // epilogue: normalized O written directly to [b*T+t][h*64+d].
  // O^T C-layout: col=q=l32 (lane-local), row=d=(r&3)+8*(r>>2)+4*hl
  const float inv = 1.f / lrun;
  const int q0 = qbi * 32;
  bf16* op = o + (size_t)(b * TT + q0 + l32) * EMBED + h * HDIM;
#pragma unroll
  for (int a = 0; a < 4; ++a) {
    ushort4v pk4;
#pragma unroll
    for (int bb = 0; bb < 4; ++bb) pk4[bb] = f2bf(oacc0[a * 4 + bb] * inv);
    *(ushort4v*)&op[a * 8 + hl * 4] = pk4;
#pragma unroll
    for (int bb = 0; bb < 4; ++bb) pk4[bb] = f2bf(oacc1[a * 4 + bb] * inv);
    *(ushort4v*)&op[32 + a * 8 + hl * 4] = pk4;
  }
}

// ---------------------------------------------------------------------------
extern "C" void kernel_launch(void* const* d_in, const int* in_sizes, int n_in,
                              void* d_out, int out_size, void* d_ws,
                              size_t ws_size, hipStream_t stream) {
  const float* x = (const float*)d_in[0];
  const float* ln1g = (const float*)d_in[1];
  const float* ln1b = (const float*)d_in[2];
  const float* wq = (const float*)d_in[3];
  const float* bq = (const float*)d_in[4];
  const float* wk = (const float*)d_in[5];
  const float* bk = (const float*)d_in[6];
  const float* wv = (const float*)d_in[7];
  const float* bv = (const float*)d_in[8];
  const float* wo = (const float*)d_in[9];
  const float* bo = (const float*)d_in[10];
  const float* ln2g = (const float*)d_in[11];
  const float* ln2b = (const float*)d_in[12];
  const float* w1 = (const float*)d_in[13];
  const float* b1 = (const float*)d_in[14];
  const float* w2 = (const float*)d_in[15];
  const float* b2 = (const float*)d_in[16];
  float* out = (float*)d_out;

  char* ws = (char*)d_ws;
  size_t off = 0;
  auto alloc = [&](size_t bytes) {
    char* p = ws + off;
    off += (bytes + 255) & ~(size_t)255;
    return p;
  };
  bf16* wqkv_t = (bf16*)alloc((size_t)2304 * 768 * 2);
  bf16* wo_t = (bf16*)alloc((size_t)768 * 768 * 2);
  bf16* w1_t = (bf16*)alloc((size_t)3072 * 768 * 2);
  bf16* w2_t = (bf16*)alloc((size_t)768 * 3072 * 2);
  bf16* h = (bf16*)alloc((size_t)MTOK * EMBED * 2);
  // qb/kb/vtb/ob dead once o-proj runs; h1 overlays them
  char* qkvo = alloc((size_t)MTOK * EMBED * 2 * 4);
  bf16* qb = (bf16*)qkvo;                       // fragment-major Q
  bf16* kb = qb + (size_t)MTOK * EMBED;         // fragment-major K
  bf16* vtb = kb + (size_t)MTOK * EMBED;        // fragment-major V
  bf16* ob = vtb + (size_t)MTOK * EMBED;
  bf16* h1 = (bf16*)qkvo;  // [MTOK][3072] bf16, overlays q/k/vt/o
  float* x1 = (float*)alloc((size_t)MTOK * EMBED * 4);
  (void)ws_size;

  TArgs ta;
  ta.src[0] = wq; ta.dst[0] = wqkv_t;                  ta.K[0] = 768;  ta.N[0] = 768;
  ta.src[1] = wk; ta.dst[1] = wqkv_t + 768 * 768;      ta.K[1] = 768;  ta.N[1] = 768;
  ta.src[2] = wv; ta.dst[2] = wqkv_t + 2 * 768 * 768;  ta.K[2] = 768;  ta.N[2] = 768;
  ta.src[3] = wo; ta.dst[3] = wo_t;                    ta.K[3] = 768;  ta.N[3] = 768;
  ta.src[4] = w1; ta.dst[4] = w1_t;                    ta.K[4] = 768;  ta.N[4] = 3072;
  ta.src[5] = w2; ta.dst[5] = w2_t;                    ta.K[5] = 3072; ta.N[5] = 768;

  transpose_k<<<dim3(2304, 1, 6), dim3(256), 0, stream>>>(ta);
  ln_k<<<dim3(MTOK / 4), dim3(256), 0, stream>>>(x, ln1g, ln1b, h);
  gemm_bt_k<0, 128><<<dim3((2304 / 128) * (MTOK / 128)), dim3(256), 0, stream>>>(
      h, wqkv_t, bq, bk, bv, nullptr, nullptr, qb, kb, vtb, 2304, 768);
  flash13_k<<<dim3(16 * HEADS * BB), dim3(256), 0, stream>>>(qb, kb, vtb, ob);
  gemm_bt_k<1, 64><<<dim3((768 / 64) * (MTOK / 128)), dim3(256), 0, stream>>>(
      ob, wo_t, bo, nullptr, nullptr, x, x1, nullptr, nullptr, nullptr, 768, 768);
  ln_k<<<dim3(MTOK / 4), dim3(256), 0, stream>>>(x1, ln2g, ln2b, h);
  gemm_bt_k<2, 128><<<dim3((3072 / 128) * (MTOK / 128)), dim3(256), 0, stream>>>(
      h, w1_t, b1, nullptr, nullptr, nullptr, nullptr, h1, nullptr, nullptr, 3072, 768);
  gemm_bt_k<1, 128><<<dim3((768 / 128) * (MTOK / 128)), dim3(256), 0, stream>>>(
      h1, w2_t, b2, nullptr, nullptr, x1, out, nullptr, nullptr, nullptr, 768, 3072);
}